// Round 1
// baseline (56.588 us; speedup 1.0000x reference)
//
#include <hip/hip_runtime.h>
#include <math.h>

// y_t = clamp(y_{t-1}, x_t, x_t+1)  -- play operator as associative clamp-scan.
// Element e=0 carries the constant function (p0,p0); e>=1 carries (k*x_e, k*x_e+1).
// compose(l, r) = apply l FIRST, then r.

#define TPB 256
#define EPT 16               // elements per thread
#define EPB (TPB * EPT)      // 4096 elements per block

struct Pair { float a, b; };

__device__ __forceinline__ Pair compose(Pair l, Pair r) {
    Pair o;
    o.a = fminf(fmaxf(l.a, r.a), r.b);
    o.b = fminf(fmaxf(l.b, r.a), r.b);
    return o;
}

__device__ __forceinline__ Pair identity_pair() {
    Pair p; p.a = -INFINITY; p.b = INFINITY; return p;
}

// ---------------- pass 1: per-block ordered reduction of clamp functions ----
__global__ __launch_bounds__(TPB)
void k_reduce(const float* __restrict__ in, const float* __restrict__ kptr,
              Pair* __restrict__ blockAgg, int n) {
    const float k = kptr[0];
    const int base = blockIdx.x * EPB + threadIdx.x * EPT;
    Pair p = identity_pair();
    if (base + EPT <= n) {
#pragma unroll
        for (int v = 0; v < EPT / 4; ++v) {
            float4 f = reinterpret_cast<const float4*>(in + base)[v];
            float xs0 = f.x, xs1 = f.y, xs2 = f.z, xs3 = f.w;
            float x[4] = {xs0, xs1, xs2, xs3};
#pragma unroll
            for (int j = 0; j < 4; ++j) {
                const int e = base + 4 * v + j;
                float lo, hi;
                if (e == 0) { lo = x[j]; hi = x[j]; }       // constant p0
                else { float xv = x[j] * k; lo = xv; hi = xv + 1.0f; }
                p.a = fminf(fmaxf(p.a, lo), hi);
                p.b = fminf(fmaxf(p.b, lo), hi);
            }
        }
    } else {
        for (int e = base; e < n; ++e) {
            float xv = in[e];
            float lo, hi;
            if (e == 0) { lo = xv; hi = xv; }
            else { xv *= k; lo = xv; hi = xv + 1.0f; }
            p.a = fminf(fmaxf(p.a, lo), hi);
            p.b = fminf(fmaxf(p.b, lo), hi);
        }
    }
    // ordered tree reduction (adjacent pairing preserves sequence order)
    __shared__ Pair s[TPB];
    s[threadIdx.x] = p;
    __syncthreads();
    for (int half = TPB / 2; half >= 1; half >>= 1) {
        Pair t;
        if ((int)threadIdx.x < half) t = compose(s[2 * threadIdx.x], s[2 * threadIdx.x + 1]);
        __syncthreads();
        if ((int)threadIdx.x < half) s[threadIdx.x] = t;
        __syncthreads();
    }
    if (threadIdx.x == 0) blockAgg[blockIdx.x] = s[0];
}

// ---------------- pass 2: exclusive scan of block aggregates (1 block) ------
__global__ __launch_bounds__(TPB)
void k_scan_blocks(const Pair* __restrict__ agg, Pair* __restrict__ pre, int nb) {
    __shared__ Pair s[TPB];
    const int per = (nb + TPB - 1) / TPB;
    const int lo = threadIdx.x * per;
    const int hi = min(lo + per, nb);
    Pair p = identity_pair();
    for (int i = lo; i < hi; ++i) p = compose(p, agg[i]);
    s[threadIdx.x] = p;
    __syncthreads();
    // Hillis-Steele inclusive scan (valid for non-commutative associative op)
    for (int off = 1; off < TPB; off <<= 1) {
        Pair t = s[threadIdx.x];
        if ((int)threadIdx.x >= off) t = compose(s[threadIdx.x - off], t);
        __syncthreads();
        s[threadIdx.x] = t;
        __syncthreads();
    }
    Pair ex = (threadIdx.x == 0) ? identity_pair() : s[threadIdx.x - 1];
    for (int i = lo; i < hi; ++i) {
        Pair cur = agg[i];
        pre[i] = ex;
        ex = compose(ex, cur);
    }
}

// ---------------- pass 3: apply — intra-block scan + per-element outputs ----
__global__ __launch_bounds__(TPB)
void k_apply(const float* __restrict__ in, const float* __restrict__ kptr,
             const Pair* __restrict__ pre, float* __restrict__ out, int n) {
    const float k = kptr[0];
    const int base = blockIdx.x * EPB + threadIdx.x * EPT;

    float xs[EPT];
    int m = 0;
    if (base + EPT <= n) {
        m = EPT;
#pragma unroll
        for (int v = 0; v < EPT / 4; ++v) {
            float4 f = reinterpret_cast<const float4*>(in + base)[v];
            xs[4 * v + 0] = f.x; xs[4 * v + 1] = f.y;
            xs[4 * v + 2] = f.z; xs[4 * v + 3] = f.w;
        }
    } else if (base < n) {
        m = n - base;
        for (int j = 0; j < m; ++j) xs[j] = in[base + j];
    }

    // thread-local aggregate
    Pair p = identity_pair();
#pragma unroll
    for (int j = 0; j < EPT; ++j) {
        if (j < m) {
            float lo, hi;
            if (base + j == 0) { lo = xs[j]; hi = xs[j]; }
            else { float xv = xs[j] * k; lo = xv; hi = xv + 1.0f; }
            p.a = fminf(fmaxf(p.a, lo), hi);
            p.b = fminf(fmaxf(p.b, lo), hi);
        }
    }

    // intra-block Hillis-Steele inclusive scan of thread aggregates
    __shared__ Pair s[TPB];
    s[threadIdx.x] = p;
    __syncthreads();
    for (int off = 1; off < TPB; off <<= 1) {
        Pair t = s[threadIdx.x];
        if ((int)threadIdx.x >= off) t = compose(s[threadIdx.x - off], t);
        __syncthreads();
        s[threadIdx.x] = t;
        __syncthreads();
    }

    // incoming function for this thread = block prefix ∘ (threads 0..tid-1)
    Pair fin = pre[blockIdx.x];
    if (threadIdx.x > 0) fin = compose(fin, s[threadIdx.x - 1]);
    // apply to dummy 0: for any prefix that includes element 0, fin is constant;
    // for block0/thread0 fin is identity and element 0 (const p0) overrides y.
    float y = fminf(fmaxf(0.0f, fin.a), fin.b);

    if (m == EPT) {
#pragma unroll
        for (int v = 0; v < EPT / 4; ++v) {
            float o0, o1, o2, o3;
#pragma unroll
            for (int j = 0; j < 4; ++j) {
                const int idx = 4 * v + j;
                float lo, hi;
                if (base + idx == 0) { lo = xs[idx]; hi = xs[idx]; }
                else { float xv = xs[idx] * k; lo = xv; hi = xv + 1.0f; }
                y = fminf(fmaxf(y, lo), hi);
                if (j == 0) o0 = y; else if (j == 1) o1 = y;
                else if (j == 2) o2 = y; else o3 = y;
            }
            float4 o = make_float4(o0, o1, o2, o3);
            reinterpret_cast<float4*>(out + base)[v] = o;
        }
    } else {
        for (int j = 0; j < m; ++j) {
            float lo, hi;
            if (base + j == 0) { lo = xs[j]; hi = xs[j]; }
            else { float xv = xs[j] * k; lo = xv; hi = xv + 1.0f; }
            y = fminf(fmaxf(y, lo), hi);
            out[base + j] = y;
        }
    }
}

extern "C" void kernel_launch(void* const* d_in, const int* in_sizes, int n_in,
                              void* d_out, int out_size, void* d_ws, size_t ws_size,
                              hipStream_t stream) {
    const float* in   = (const float*)d_in[0];   // [T+1], in[0] = p0
    const float* kptr = (const float*)d_in[1];   // scalar weight
    float* out = (float*)d_out;                  // [T+1]
    const int n  = in_sizes[0];                  // T+1 elements (scan domain)
    const int nb = (n + EPB - 1) / EPB;

    Pair* agg = (Pair*)d_ws;     // nb aggregates
    Pair* pre = agg + nb;        // nb exclusive prefixes

    k_reduce<<<nb, TPB, 0, stream>>>(in, kptr, agg, n);
    k_scan_blocks<<<1, TPB, 0, stream>>>(agg, pre, nb);
    k_apply<<<nb, TPB, 0, stream>>>(in, kptr, pre, out, n);
}